// Round 6
// baseline (406.809 us; speedup 1.0000x reference)
//
#include <hip/hip_runtime.h>

#define N_ROWS 262144
#define DIM 64
#define KCODES 512
#define TAU_S  6e-3f    // score-margin flag threshold (dist margin = 2x = 1.2e-2)
#define TAU_SC 4e-3f    // scalar fallback (round-3 proven)
#define BSTRIDE 136     // shorts per code slot in LDS: 272 B = 17*16B (odd 16B mult)

typedef __attribute__((ext_vector_type(8))) short bf16x8;
typedef __attribute__((ext_vector_type(4))) float f32x4;

static __device__ __forceinline__ short f2bf(float f) {   // RNE float->bf16
    union { float f; unsigned u; } c; c.f = f;
    unsigned r = (c.u + 0x7fff + ((c.u >> 16) & 1)) >> 16;
    return (short)r;
}
static __device__ __forceinline__ float bf2f(short b) {
    union { float f; unsigned u; } c;
    c.u = ((unsigned)(unsigned short)b) << 16;
    return c.f;
}

// ---- init: eT f32 [K][D], Bg bf16 [K][hi(64)|lo(64)], e2h = -0.5*e2 --------
__global__ void vq_init(const float* __restrict__ e, float* __restrict__ eT,
                        short* __restrict__ Bg, float* __restrict__ e2h,
                        float* __restrict__ loss_slot) {
    int idx = blockIdx.x * 256 + threadIdx.x;   // grid covers 32768
    if (idx < KCODES * DIM) {
        int k = idx >> 6, d = idx & 63;
        float v = e[d * KCODES + k];
        eT[k * DIM + d] = v;
        short hi = f2bf(v);
        float lo = v - bf2f(hi);                // exact (Sterbenz)
        Bg[k * 128 + d] = hi;
        Bg[k * 128 + 64 + d] = f2bf(lo);
    }
    if (idx < KCODES) {
        double s = 0.0;
        for (int d = 0; d < DIM; ++d) {
            double v = (double)e[d * KCODES + idx];
            s = fma(v, v, s);
        }
        e2h[idx] = (float)(-0.5 * s);
    }
    if (idx == 0) *loss_slot = 0.f;
}

__global__ void vq_zero_loss(float* __restrict__ loss_slot) { *loss_slot = 0.f; }

// ---- wave-cooperative exact fp64 rescan of one row (all 64 lanes call) -----
__device__ inline void wave_rescan(const float* __restrict__ x,
                                   const float* __restrict__ e,  // [D][K]
                                   int row, double* outDist, int* outK) {
    const int lane = threadIdx.x & 63;
    const float* xr = x + (size_t)row * DIM;
    double x2d = 0.0;
    for (int d = 0; d < DIM; ++d) {
        double xd = (double)xr[d];
        x2d = fma(xd, xd, x2d);
    }
    double best = 1e300; int bk = 0;
    for (int j = 0; j < 8; ++j) {
        const int k = lane + (j << 6);
        double dot = 0.0, e2 = 0.0;
        for (int d = 0; d < DIM; ++d) {
            double xd = (double)xr[d];
            double ev = (double)e[d * KCODES + k];
            dot = fma(xd, ev, dot);
            e2 = fma(ev, ev, e2);
        }
        double dist = fma(-2.0, dot, x2d + e2);
        if (dist < best) { best = dist; bk = k; }
    }
    #pragma unroll
    for (int off = 32; off; off >>= 1) {
        double od = __shfl_xor(best, off);
        int ok = __shfl_xor(bk, off);
        if (od < best || (od == best && ok < bk)) { best = od; bk = ok; }
    }
    *outDist = best; *outK = bk;
}

// ---- main: full codebook in LDS; 1024 thr (16 waves, 4/SIMD), 1 block/CU ---
__global__ __launch_bounds__(1024) void vq_mfma(
    const float* __restrict__ x, const float* __restrict__ e,
    const float* __restrict__ eT, const short* __restrict__ Bg,
    const float* __restrict__ e2h,
    float* __restrict__ out, float* __restrict__ loss_slot) {

    __shared__ short shB[KCODES * BSTRIDE];   // 139264 B: [code][hi64|lo64|e2|pad]

    const int tid = threadIdx.x;
    const int lane = tid & 63;
    const int n = lane & 15;           // MFMA col (code within chunk) / A row
    const int q = lane >> 4;           // quad
    const int wav = tid >> 6;          // 0..15

    // ---- stage entire codebook + e2h into LDS (once; then read-only) ----
    {
        const float4* src = (const float4*)Bg;
        #pragma unroll
        for (int i = 0; i < 8; ++i) {
            int idx = tid + 1024 * i;          // float4 index over 128 KB
            int code = idx >> 4, off = idx & 15;
            *(float4*)&shB[code * BSTRIDE + off * 8] = src[idx];
        }
        if (tid < KCODES) *(float*)&shB[tid * BSTRIDE + 128] = e2h[tid];
    }
    __syncthreads();

    for (int t = 0; t < 2; ++t) {
        const int wbase = (blockIdx.x * 2 + t) * 512 + wav * 32;

        // ---- A fragments (hi/lo) + C-layout x2 for 2 strips of 16 rows ----
        bf16x8 Ah0[2], Ah1[2], Al0[2], Al1[2];
        float x2c[2][4];
        #pragma unroll
        for (int s = 0; s < 2; ++s) {
            const int row = wbase + s * 16 + n;        // A-layout row = lane&15
            const float4* xr = (const float4*)(x + (size_t)row * DIM);
            float4 f0 = xr[2*q], f1 = xr[2*q+1], f2 = xr[8+2*q], f3 = xr[9+2*q];
            float v0s[8] = {f0.x,f0.y,f0.z,f0.w,f1.x,f1.y,f1.z,f1.w};
            float v1s[8] = {f2.x,f2.y,f2.z,f2.w,f3.x,f3.y,f3.z,f3.w};
            float p = 0.f;
            #pragma unroll
            for (int j = 0; j < 8; ++j) {
                float v0 = v0s[j], v1 = v1s[j];
                short h0 = f2bf(v0), h1 = f2bf(v1);
                Ah0[s][j] = h0;            Ah1[s][j] = h1;
                Al0[s][j] = f2bf(v0 - bf2f(h0));
                Al1[s][j] = f2bf(v1 - bf2f(h1));
                p = fmaf(v0, v0, p);
                p = fmaf(v1, v1, p);
            }
            p += __shfl_xor(p, 16);
            p += __shfl_xor(p, 32);
            #pragma unroll
            for (int r = 0; r < 4; ++r)
                x2c[s][r] = __shfl(p, 4 * q + r);
        }

        float best[2][4], sec[2][4];
        #pragma unroll
        for (int s = 0; s < 2; ++s)
            #pragma unroll
            for (int r = 0; r < 4; ++r) { best[s][r] = -3.4e38f; sec[s][r] = -3.4e38f; }

        bf16x8 Ba[4], Bb[4];
        float ea, eb;

        auto loadB = [&](bf16x8* Bf, float& ev, int ch) {
            const short* bp = &shB[(ch * 16 + n) * BSTRIDE + q * 8];
            Bf[0] = *(const bf16x8*)(bp);        // hi, dims 0..31 (k = 8q+j)
            Bf[1] = *(const bf16x8*)(bp + 32);   // hi, dims 32..63
            Bf[2] = *(const bf16x8*)(bp + 64);   // lo, dims 0..31
            Bf[3] = *(const bf16x8*)(bp + 96);   // lo, dims 32..63
            ev = *(const float*)&shB[(ch * 16 + n) * BSTRIDE + 128];  // -0.5*e2
        };

        auto proc = [&](const bf16x8* Bf, float ev, int ch) {
            const unsigned chid = 31u - (unsigned)ch;   // bigger = earlier chunk
            #pragma unroll
            for (int s = 0; s < 2; ++s) {
                f32x4 acc = {ev, ev, ev, ev};           // score = dot - 0.5*e2
                acc = __builtin_amdgcn_mfma_f32_16x16x32_bf16(Ah0[s], Bf[0], acc, 0, 0, 0);
                acc = __builtin_amdgcn_mfma_f32_16x16x32_bf16(Ah1[s], Bf[1], acc, 0, 0, 0);
                acc = __builtin_amdgcn_mfma_f32_16x16x32_bf16(Ah0[s], Bf[2], acc, 0, 0, 0);
                acc = __builtin_amdgcn_mfma_f32_16x16x32_bf16(Ah1[s], Bf[3], acc, 0, 0, 0);
                acc = __builtin_amdgcn_mfma_f32_16x16x32_bf16(Al0[s], Bf[0], acc, 0, 0, 0);
                acc = __builtin_amdgcn_mfma_f32_16x16x32_bf16(Al1[s], Bf[1], acc, 0, 0, 0);
                // lo*lo dropped: |err| ~1e-4 << TAU_S, certified below
                #pragma unroll
                for (int r = 0; r < 4; ++r) {
                    unsigned kb = (__float_as_uint(acc[r]) & 0xFFFFFFE0u) | chid;
                    float key = __uint_as_float(kb);
                    float mn = fminf(best[s][r], key);
                    sec[s][r] = fmaxf(sec[s][r], mn);
                    best[s][r] = fmaxf(best[s][r], key);
                }
            }
        };

        // ping-pong LDS prefetch over 32 chunks of 16 codes
        loadB(Ba, ea, 0);
        for (int ch = 0; ch < 32; ch += 2) {
            loadB(Bb, eb, ch + 1);
            proc(Ba, ea, ch);
            if (ch + 2 < 32) loadB(Ba, ea, ch + 2);
            proc(Bb, eb, ch + 1);
        }

        // ---- unpack winner, cross-lane top-2 merge over the 16 cols ----
        int kidx[2][4];
        #pragma unroll
        for (int s = 0; s < 2; ++s)
            #pragma unroll
            for (int r = 0; r < 4; ++r) {
                int ch = 31 - (int)(__float_as_uint(best[s][r]) & 31u);
                kidx[s][r] = (ch << 4) | n;
            }
        #pragma unroll
        for (int off = 1; off <= 8; off <<= 1) {
            #pragma unroll
            for (int s = 0; s < 2; ++s)
                #pragma unroll
                for (int r = 0; r < 4; ++r) {
                    float ob = __shfl_xor(best[s][r], off);
                    float os = __shfl_xor(sec[s][r], off);
                    int   ok = __shfl_xor(kidx[s][r], off);
                    float mn = fminf(best[s][r], ob);
                    sec[s][r] = fmaxf(fmaxf(sec[s][r], os), mn);
                    bool take = (ob > best[s][r]) || (ob == best[s][r] && ok < kidx[s][r]);
                    best[s][r] = take ? ob : best[s][r];
                    kidx[s][r] = take ? ok : kidx[s][r];
                }
        }

        // dist = x2 - 2*score (masked score err ~32ulp, << loss threshold)
        float lossd[2][4];
        #pragma unroll
        for (int s = 0; s < 2; ++s)
            #pragma unroll
            for (int r = 0; r < 4; ++r)
                lossd[s][r] = fmaf(-2.f, best[s][r], x2c[s][r]);

        // ---- rare fp64 certify/rescan for thin-margin rows ----
        #pragma unroll
        for (int s = 0; s < 2; ++s)
            for (int r = 0; r < 4; ++r) {
                unsigned long long m =
                    __ballot((best[s][r] - sec[s][r] < TAU_S) && (n == 0));
                while (m) {
                    int l = __builtin_ctzll(m);
                    m &= m - 1;
                    int qq = l >> 4;
                    double bd; int bk;
                    wave_rescan(x, e, wbase + s * 16 + 4 * qq + r, &bd, &bk);
                    if (q == qq) { lossd[s][r] = (float)bd; kidx[s][r] = bk; }
                }
            }

        // ---- write quantized rows + loss ----
        float lp = 0.f;
        #pragma unroll
        for (int s = 0; s < 2; ++s)
            #pragma unroll
            for (int r = 0; r < 4; ++r) {
                int row = wbase + s * 16 + 4 * q + r;
                const float4* src = (const float4*)(eT + (size_t)kidx[s][r] * DIM);
                ((float4*)(out + (size_t)row * DIM))[n] = src[n];
                if (n == 0) lp += lossd[s][r];
            }
        #pragma unroll
        for (int off = 1; off < 64; off <<= 1) lp += __shfl_xor(lp, off);
        if (lane == 0)
            atomicAdd(loss_slot, lp * (1.25f / ((float)N_ROWS * (float)DIM)));
    }
}

// ---- fallback (no workspace): round-3 scalar kernel, 2 rows/thread ---------
__global__ __launch_bounds__(256, 2) void vq_scalar(
    const float* __restrict__ x, const float* __restrict__ e,
    float* __restrict__ out, float* __restrict__ loss_slot) {

    __shared__ float sh[128 * 68];
    __shared__ float red[256];
    const int tid = threadIdx.x;
    const int blockBase = blockIdx.x * 512;
    const int r0 = blockBase + tid, r1 = r0 + 256;

    float xa[DIM], xb[DIM];
    {
        const float4* xr0 = (const float4*)(x + (size_t)r0 * DIM);
        const float4* xr1 = (const float4*)(x + (size_t)r1 * DIM);
        #pragma unroll
        for (int j = 0; j < 16; ++j) {
            float4 v0 = xr0[j], v1 = xr1[j];
            xa[4*j]=v0.x; xa[4*j+1]=v0.y; xa[4*j+2]=v0.z; xa[4*j+3]=v0.w;
            xb[4*j]=v1.x; xb[4*j+1]=v1.y; xb[4*j+2]=v1.z; xb[4*j+3]=v1.w;
        }
    }
    float x2a = 0.f, x2b = 0.f;
    #pragma unroll
    for (int d = 0; d < DIM; ++d) { x2a = fmaf(xa[d], xa[d], x2a); x2b = fmaf(xb[d], xb[d], x2b); }

    float bestA = 3.4e38f, secA = 3.4e38f, bestB = 3.4e38f, secB = 3.4e38f;
    int bkA = 0, bkB = 0;

    for (int kb = 0; kb < KCODES; kb += 128) {
        for (int idx = tid; idx < 128 * DIM; idx += 256) {
            int d = idx >> 7, c = idx & 127;
            sh[c * 68 + d] = e[d * KCODES + kb + c];
        }
        __syncthreads();
        if (tid < 128) {
            float ssum = 0.f;
            for (int d = 0; d < DIM; ++d) { float v = sh[tid * 68 + d]; ssum = fmaf(v, v, ssum); }
            sh[tid * 68 + 64] = ssum;
        }
        __syncthreads();
        for (int k = 0; k < 128; ++k) {
            const float* ck = sh + k * 68;
            float a0=0.f,a1=0.f,b0=0.f,b1=0.f;
            #pragma unroll
            for (int j = 0; j < 16; j += 2) {
                float4 c0 = *(const float4*)(ck + 4*j);
                float4 c1 = *(const float4*)(ck + 4*j + 4);
                a0=fmaf(xa[4*j],c0.x,a0); a0=fmaf(xa[4*j+1],c0.y,a0); a0=fmaf(xa[4*j+2],c0.z,a0); a0=fmaf(xa[4*j+3],c0.w,a0);
                b0=fmaf(xb[4*j],c0.x,b0); b0=fmaf(xb[4*j+1],c0.y,b0); b0=fmaf(xb[4*j+2],c0.z,b0); b0=fmaf(xb[4*j+3],c0.w,b0);
                a1=fmaf(xa[4*j+4],c1.x,a1); a1=fmaf(xa[4*j+5],c1.y,a1); a1=fmaf(xa[4*j+6],c1.z,a1); a1=fmaf(xa[4*j+7],c1.w,a1);
                b1=fmaf(xb[4*j+4],c1.x,b1); b1=fmaf(xb[4*j+5],c1.y,b1); b1=fmaf(xb[4*j+6],c1.z,b1); b1=fmaf(xb[4*j+7],c1.w,b1);
            }
            const float e2k = ck[64]; const int kg = kb + k;
            const float dA = fmaf(-2.f, a0 + a1, x2a + e2k);
            const float dB = fmaf(-2.f, b0 + b1, x2b + e2k);
            if (dA < bestA) { secA = bestA; bestA = dA; bkA = kg; } else if (dA < secA) secA = dA;
            if (dB < bestB) { secB = bestB; bestB = dB; bkB = kg; } else if (dB < secB) secB = dB;
        }
        __syncthreads();
    }

    const int lane = tid & 63;
    const int waveBase = blockBase + (tid & ~63);
    unsigned long long m = __ballot(secA - bestA < TAU_SC);
    while (m) {
        int l = __builtin_ctzll(m); m &= m - 1;
        double bd; int bk2;
        wave_rescan(x, e, waveBase + l, &bd, &bk2);
        if (lane == l) { bestA = (float)bd; bkA = bk2; }
    }
    m = __ballot(secB - bestB < TAU_SC);
    while (m) {
        int l = __builtin_ctzll(m); m &= m - 1;
        double bd; int bk2;
        wave_rescan(x, e, waveBase + 256 + l, &bd, &bk2);
        if (lane == l) { bestB = (float)bd; bkB = bk2; }
    }

    float4* o0 = (float4*)(out + (size_t)r0 * DIM);
    float4* o1 = (float4*)(out + (size_t)r1 * DIM);
    #pragma unroll
    for (int j = 0; j < 16; ++j) {
        float4 va, vb;
        va.x=e[(4*j)*KCODES+bkA]; vb.x=e[(4*j)*KCODES+bkB];
        va.y=e[(4*j+1)*KCODES+bkA]; vb.y=e[(4*j+1)*KCODES+bkB];
        va.z=e[(4*j+2)*KCODES+bkA]; vb.z=e[(4*j+2)*KCODES+bkB];
        va.w=e[(4*j+3)*KCODES+bkA]; vb.w=e[(4*j+3)*KCODES+bkB];
        o0[j]=va; o1[j]=vb;
    }

    red[tid] = bestA + bestB;
    __syncthreads();
    #pragma unroll
    for (int s2 = 128; s2 > 0; s2 >>= 1) {
        if (tid < s2) red[tid] += red[tid + s2];
        __syncthreads();
    }
    if (tid == 0) atomicAdd(loss_slot, red[0] * (1.25f / ((float)N_ROWS * (float)DIM)));
}

extern "C" void kernel_launch(void* const* d_in, const int* in_sizes, int n_in,
                              void* d_out, int out_size, void* d_ws, size_t ws_size,
                              hipStream_t stream) {
    const float* x = (const float*)d_in[0];   // [N, D]
    const float* e = (const float*)d_in[1];   // [D, K]
    float* out = (float*)d_out;               // N*D quantized + 1 loss
    float* loss_slot = out + (size_t)N_ROWS * DIM;

    // ws: eT f32 @0 (131072) | Bg bf16 @131072 (131072) | e2h @262144 (2048)
    const size_t ws_needed = 131072 + 131072 + 2048;

    if (ws_size >= ws_needed) {
        float* eT = (float*)d_ws;
        short* Bg = (short*)((char*)d_ws + 131072);
        float* e2h = (float*)((char*)d_ws + 262144);
        vq_init<<<128, 256, 0, stream>>>(e, eT, Bg, e2h, loss_slot);
        vq_mfma<<<256, 1024, 0, stream>>>(x, e, eT, Bg, e2h, out, loss_slot);
    } else {
        vq_zero_loss<<<1, 1, 0, stream>>>(loss_slot);
        vq_scalar<<<N_ROWS / 512, 256, 0, stream>>>(x, e, out, loss_slot);
    }
}

// Round 7
// 253.559 us; speedup vs baseline: 1.6044x; 1.6044x over previous
//
#include <hip/hip_runtime.h>

#define N_ROWS 262144
#define DIM 64
#define KCODES 512
#define TAU_S  6e-3f    // score-margin flag threshold (dist margin = 2x = 1.2e-2)
#define TAU_SC 4e-3f    // scalar fallback (round-3 proven)

typedef __attribute__((ext_vector_type(8))) short bf16x8;
typedef __attribute__((ext_vector_type(4))) float f32x4;

static __device__ __forceinline__ short f2bf(float f) {   // RNE float->bf16
    union { float f; unsigned u; } c; c.f = f;
    unsigned r = (c.u + 0x7fff + ((c.u >> 16) & 1)) >> 16;
    return (short)r;
}
static __device__ __forceinline__ float bf2f(short b) {
    union { float f; unsigned u; } c;
    c.u = ((unsigned)(unsigned short)b) << 16;
    return c.f;
}

// ---- init ------------------------------------------------------------------
// eT  f32 [K][D]                       (exact output gather)
// Bc  bf16 chunk-part-major: [ch][part][n][q][j] shorts,
//     part: 0=hi d0..31, 1=hi d32..63, 2=lo d0..31, 3=lo d32..63
//     index = ch*2048 + part*512 + n*32 + q*8 + j   (per-part wave load = 1KB contig)
// e2h f32 [K] = -0.5*||e_k||^2 (fp64-accurate)
__global__ void vq_init(const float* __restrict__ e, float* __restrict__ eT,
                        short* __restrict__ Bc, float* __restrict__ e2h,
                        float* __restrict__ loss_slot) {
    int idx = blockIdx.x * 256 + threadIdx.x;   // grid covers 32768
    if (idx < KCODES * DIM) {
        int k = idx >> 6, d = idx & 63;
        float v = e[d * KCODES + k];
        eT[k * DIM + d] = v;
        short hi = f2bf(v);
        short lo = f2bf(v - bf2f(hi));          // hi-residual, then RNE to bf16
        int ch = k >> 4, n = k & 15, q = (d >> 3) & 3, j = d & 7, half = d >> 5;
        Bc[ch * 2048 + (half)     * 512 + n * 32 + q * 8 + j] = hi;
        Bc[ch * 2048 + (2 + half) * 512 + n * 32 + q * 8 + j] = lo;
    }
    if (idx < KCODES) {
        double s = 0.0;
        for (int d = 0; d < DIM; ++d) {
            double v = (double)e[d * KCODES + idx];
            s = fma(v, v, s);
        }
        e2h[idx] = (float)(-0.5 * s);
    }
    if (idx == 0) *loss_slot = 0.f;
}

__global__ void vq_zero_loss(float* __restrict__ loss_slot) { *loss_slot = 0.f; }

// ---- wave-cooperative exact fp64 rescan of one row (all 64 lanes call) -----
__device__ inline void wave_rescan(const float* __restrict__ x,
                                   const float* __restrict__ e,  // [D][K]
                                   int row, double* outDist, int* outK) {
    const int lane = threadIdx.x & 63;
    const float* xr = x + (size_t)row * DIM;
    double x2d = 0.0;
    for (int d = 0; d < DIM; ++d) {
        double xd = (double)xr[d];
        x2d = fma(xd, xd, x2d);
    }
    double best = 1e300; int bk = 0;
    for (int j = 0; j < 8; ++j) {
        const int k = lane + (j << 6);
        double dot = 0.0, e2 = 0.0;
        for (int d = 0; d < DIM; ++d) {
            double xd = (double)xr[d];
            double ev = (double)e[d * KCODES + k];
            dot = fma(xd, ev, dot);
            e2 = fma(ev, ev, e2);
        }
        double dist = fma(-2.0, dot, x2d + e2);
        if (dist < best) { best = dist; bk = k; }
    }
    #pragma unroll
    for (int off = 32; off; off >>= 1) {
        double od = __shfl_xor(best, off);
        int ok = __shfl_xor(bk, off);
        if (od < best || (od == best && ok < bk)) { best = od; bk = ok; }
    }
    *outDist = best; *outK = bk;
}

// ---- main: 64 rows/wave, global-B ping-pong, no hot-loop barriers ----------
// __launch_bounds__(256,2): 2 waves/EU min -> 256-reg unified cap. The kernel
// needs ~185 live regs; the old 4-wave/EU bound (128 cap) forced spills that
// were the r4-r6 limiter (VGPR_Count pinned at 64).
__global__ __launch_bounds__(256, 2) void vq_mfma(
    const float* __restrict__ x, const float* __restrict__ e,
    const float* __restrict__ eT, const short* __restrict__ Bc,
    const float* __restrict__ e2h,
    float* __restrict__ out, float* __restrict__ loss_slot) {

    __shared__ float she2[KCODES];     // 2 KB: -0.5*e2, staged once

    const int tid = threadIdx.x;
    const int lane = tid & 63;
    const int n = lane & 15;           // MFMA col (code within chunk) / A row
    const int q = lane >> 4;           // quad
    const int wav = tid >> 6;          // 0..3
    const int wbase = blockIdx.x * 256 + wav * 64;   // 64 rows per wave

    for (int i = tid; i < KCODES; i += 256) she2[i] = e2h[i];
    __syncthreads();                   // only barrier in the kernel

    // ---- A fragments (hi/lo) + C-layout x2 for 4 strips of 16 rows ----
    bf16x8 Ah0[4], Ah1[4], Al0[4], Al1[4];
    float x2c[4][4];
    #pragma unroll
    for (int s = 0; s < 4; ++s) {
        const int row = wbase + s * 16 + n;            // A-layout row = lane&15
        const float4* xr = (const float4*)(x + (size_t)row * DIM);
        float4 f0 = xr[2*q], f1 = xr[2*q+1], f2 = xr[8+2*q], f3 = xr[9+2*q];
        float v0s[8] = {f0.x,f0.y,f0.z,f0.w,f1.x,f1.y,f1.z,f1.w};   // dims 8q..
        float v1s[8] = {f2.x,f2.y,f2.z,f2.w,f3.x,f3.y,f3.z,f3.w};   // dims 32+8q..
        float p = 0.f;
        #pragma unroll
        for (int j = 0; j < 8; ++j) {
            float v0 = v0s[j], v1 = v1s[j];
            short h0 = f2bf(v0), h1 = f2bf(v1);
            Ah0[s][j] = h0;            Ah1[s][j] = h1;
            Al0[s][j] = f2bf(v0 - bf2f(h0));
            Al1[s][j] = f2bf(v1 - bf2f(h1));
            p = fmaf(v0, v0, p);
            p = fmaf(v1, v1, p);
        }
        p += __shfl_xor(p, 16);        // lanes {n,n+16,n+32,n+48} -> full x2
        p += __shfl_xor(p, 32);
        #pragma unroll
        for (int r = 0; r < 4; ++r)    // C-layout row 4q+r held by src lane 4q+r
            x2c[s][r] = __shfl(p, 4 * q + r);
    }

    float best[4][4], sec[4][4];
    #pragma unroll
    for (int s = 0; s < 4; ++s)
        #pragma unroll
        for (int r = 0; r < 4; ++r) { best[s][r] = -3.4e38f; sec[s][r] = -3.4e38f; }

    bf16x8 Ba[4], Bb[4];
    float ea, eb;

    auto loadB = [&](bf16x8* Bf, float& ev, int ch) {
        const short* bp = Bc + ch * 2048 + n * 32 + q * 8;
        Bf[0] = *(const bf16x8*)(bp);           // hi d0..31  (k = 8q+j)
        Bf[1] = *(const bf16x8*)(bp + 512);     // hi d32..63
        Bf[2] = *(const bf16x8*)(bp + 1024);    // lo d0..31
        Bf[3] = *(const bf16x8*)(bp + 1536);    // lo d32..63
        ev = she2[ch * 16 + n];                 // -0.5*e2 (16 banks, broadcast)
    };

    auto proc = [&](const bf16x8* Bf, float ev, int ch) {
        const unsigned chid = 31u - (unsigned)ch;   // bigger = earlier chunk
        #pragma unroll
        for (int s = 0; s < 4; ++s) {
            f32x4 acc = {ev, ev, ev, ev};           // score = dot - 0.5*e2
            acc = __builtin_amdgcn_mfma_f32_16x16x32_bf16(Ah0[s], Bf[0], acc, 0, 0, 0);
            acc = __builtin_amdgcn_mfma_f32_16x16x32_bf16(Ah1[s], Bf[1], acc, 0, 0, 0);
            acc = __builtin_amdgcn_mfma_f32_16x16x32_bf16(Ah0[s], Bf[2], acc, 0, 0, 0);
            acc = __builtin_amdgcn_mfma_f32_16x16x32_bf16(Ah1[s], Bf[3], acc, 0, 0, 0);
            acc = __builtin_amdgcn_mfma_f32_16x16x32_bf16(Al0[s], Bf[0], acc, 0, 0, 0);
            acc = __builtin_amdgcn_mfma_f32_16x16x32_bf16(Al1[s], Bf[1], acc, 0, 0, 0);
            // lo*lo dropped: |err| ~1e-4 << TAU_S, certified below
            #pragma unroll
            for (int r = 0; r < 4; ++r) {
                unsigned kb = (__float_as_uint(acc[r]) & 0xFFFFFFE0u) | chid;
                float key = __uint_as_float(kb);
                float mn = fminf(best[s][r], key);
                sec[s][r] = fmaxf(sec[s][r], mn);
                best[s][r] = fmaxf(best[s][r], key);
            }
        }
    };

    // ping-pong global (L2-hot) prefetch over 32 chunks of 16 codes
    loadB(Ba, ea, 0);
    for (int ch = 0; ch < 32; ch += 2) {
        loadB(Bb, eb, ch + 1);
        proc(Ba, ea, ch);
        if (ch + 2 < 32) loadB(Ba, ea, ch + 2);
        proc(Bb, eb, ch + 1);
    }

    // ---- unpack winner, cross-lane top-2 merge over the 16 cols ----
    int kidx[4][4];
    #pragma unroll
    for (int s = 0; s < 4; ++s)
        #pragma unroll
        for (int r = 0; r < 4; ++r) {
            int ch = 31 - (int)(__float_as_uint(best[s][r]) & 31u);
            kidx[s][r] = (ch << 4) | n;
        }
    #pragma unroll
    for (int off = 1; off <= 8; off <<= 1) {
        #pragma unroll
        for (int s = 0; s < 4; ++s)
            #pragma unroll
            for (int r = 0; r < 4; ++r) {
                float ob = __shfl_xor(best[s][r], off);
                float os = __shfl_xor(sec[s][r], off);
                int   ok = __shfl_xor(kidx[s][r], off);
                float mn = fminf(best[s][r], ob);
                sec[s][r] = fmaxf(fmaxf(sec[s][r], os), mn);
                bool take = (ob > best[s][r]) || (ob == best[s][r] && ok < kidx[s][r]);
                best[s][r] = take ? ob : best[s][r];
                kidx[s][r] = take ? ok : kidx[s][r];
            }
    }

    // dist = x2 - 2*score (masked score err ~32ulp, << loss threshold)
    float lossd[4][4];
    #pragma unroll
    for (int s = 0; s < 4; ++s)
        #pragma unroll
        for (int r = 0; r < 4; ++r)
            lossd[s][r] = fmaf(-2.f, best[s][r], x2c[s][r]);

    // ---- rare fp64 certify/rescan for thin-margin rows ----
    #pragma unroll
    for (int s = 0; s < 4; ++s)
        for (int r = 0; r < 4; ++r) {
            unsigned long long m =
                __ballot((best[s][r] - sec[s][r] < TAU_S) && (n == 0));
            while (m) {
                int l = __builtin_ctzll(m);
                m &= m - 1;
                int qq = l >> 4;
                double bd; int bk;
                wave_rescan(x, e, wbase + s * 16 + 4 * qq + r, &bd, &bk);
                if (q == qq) { lossd[s][r] = (float)bd; kidx[s][r] = bk; }
            }
        }

    // ---- write quantized rows + loss ----
    float lp = 0.f;
    #pragma unroll
    for (int s = 0; s < 4; ++s)
        #pragma unroll
        for (int r = 0; r < 4; ++r) {
            int row = wbase + s * 16 + 4 * q + r;
            const float4* src = (const float4*)(eT + (size_t)kidx[s][r] * DIM);
            ((float4*)(out + (size_t)row * DIM))[n] = src[n];
            if (n == 0) lp += lossd[s][r];
        }
    #pragma unroll
    for (int off = 1; off < 64; off <<= 1) lp += __shfl_xor(lp, off);
    if (lane == 0)
        atomicAdd(loss_slot, lp * (1.25f / ((float)N_ROWS * (float)DIM)));
}

// ---- fallback (no workspace): round-3 scalar kernel, 2 rows/thread ---------
__global__ __launch_bounds__(256, 2) void vq_scalar(
    const float* __restrict__ x, const float* __restrict__ e,
    float* __restrict__ out, float* __restrict__ loss_slot) {

    __shared__ float sh[128 * 68];
    __shared__ float red[256];
    const int tid = threadIdx.x;
    const int blockBase = blockIdx.x * 512;
    const int r0 = blockBase + tid, r1 = r0 + 256;

    float xa[DIM], xb[DIM];
    {
        const float4* xr0 = (const float4*)(x + (size_t)r0 * DIM);
        const float4* xr1 = (const float4*)(x + (size_t)r1 * DIM);
        #pragma unroll
        for (int j = 0; j < 16; ++j) {
            float4 v0 = xr0[j], v1 = xr1[j];
            xa[4*j]=v0.x; xa[4*j+1]=v0.y; xa[4*j+2]=v0.z; xa[4*j+3]=v0.w;
            xb[4*j]=v1.x; xb[4*j+1]=v1.y; xb[4*j+2]=v1.z; xb[4*j+3]=v1.w;
        }
    }
    float x2a = 0.f, x2b = 0.f;
    #pragma unroll
    for (int d = 0; d < DIM; ++d) { x2a = fmaf(xa[d], xa[d], x2a); x2b = fmaf(xb[d], xb[d], x2b); }

    float bestA = 3.4e38f, secA = 3.4e38f, bestB = 3.4e38f, secB = 3.4e38f;
    int bkA = 0, bkB = 0;

    for (int kb = 0; kb < KCODES; kb += 128) {
        for (int idx = tid; idx < 128 * DIM; idx += 256) {
            int d = idx >> 7, c = idx & 127;
            sh[c * 68 + d] = e[d * KCODES + kb + c];
        }
        __syncthreads();
        if (tid < 128) {
            float ssum = 0.f;
            for (int d = 0; d < DIM; ++d) { float v = sh[tid * 68 + d]; ssum = fmaf(v, v, ssum); }
            sh[tid * 68 + 64] = ssum;
        }
        __syncthreads();
        for (int k = 0; k < 128; ++k) {
            const float* ck = sh + k * 68;
            float a0=0.f,a1=0.f,b0=0.f,b1=0.f;
            #pragma unroll
            for (int j = 0; j < 16; j += 2) {
                float4 c0 = *(const float4*)(ck + 4*j);
                float4 c1 = *(const float4*)(ck + 4*j + 4);
                a0=fmaf(xa[4*j],c0.x,a0); a0=fmaf(xa[4*j+1],c0.y,a0); a0=fmaf(xa[4*j+2],c0.z,a0); a0=fmaf(xa[4*j+3],c0.w,a0);
                b0=fmaf(xb[4*j],c0.x,b0); b0=fmaf(xb[4*j+1],c0.y,b0); b0=fmaf(xb[4*j+2],c0.z,b0); b0=fmaf(xb[4*j+3],c0.w,b0);
                a1=fmaf(xa[4*j+4],c1.x,a1); a1=fmaf(xa[4*j+5],c1.y,a1); a1=fmaf(xa[4*j+6],c1.z,a1); a1=fmaf(xa[4*j+7],c1.w,a1);
                b1=fmaf(xb[4*j+4],c1.x,b1); b1=fmaf(xb[4*j+5],c1.y,b1); b1=fmaf(xb[4*j+6],c1.z,b1); b1=fmaf(xb[4*j+7],c1.w,b1);
            }
            const float e2k = ck[64]; const int kg = kb + k;
            const float dA = fmaf(-2.f, a0 + a1, x2a + e2k);
            const float dB = fmaf(-2.f, b0 + b1, x2b + e2k);
            if (dA < bestA) { secA = bestA; bestA = dA; bkA = kg; } else if (dA < secA) secA = dA;
            if (dB < bestB) { secB = bestB; bestB = dB; bkB = kg; } else if (dB < secB) secB = dB;
        }
        __syncthreads();
    }

    const int lane = tid & 63;
    const int waveBase = blockBase + (tid & ~63);
    unsigned long long m = __ballot(secA - bestA < TAU_SC);
    while (m) {
        int l = __builtin_ctzll(m); m &= m - 1;
        double bd; int bk2;
        wave_rescan(x, e, waveBase + l, &bd, &bk2);
        if (lane == l) { bestA = (float)bd; bkA = bk2; }
    }
    m = __ballot(secB - bestB < TAU_SC);
    while (m) {
        int l = __builtin_ctzll(m); m &= m - 1;
        double bd; int bk2;
        wave_rescan(x, e, waveBase + 256 + l, &bd, &bk2);
        if (lane == l) { bestB = (float)bd; bkB = bk2; }
    }

    float4* o0 = (float4*)(out + (size_t)r0 * DIM);
    float4* o1 = (float4*)(out + (size_t)r1 * DIM);
    #pragma unroll
    for (int j = 0; j < 16; ++j) {
        float4 va, vb;
        va.x=e[(4*j)*KCODES+bkA]; vb.x=e[(4*j)*KCODES+bkB];
        va.y=e[(4*j+1)*KCODES+bkA]; vb.y=e[(4*j+1)*KCODES+bkB];
        va.z=e[(4*j+2)*KCODES+bkA]; vb.z=e[(4*j+2)*KCODES+bkB];
        va.w=e[(4*j+3)*KCODES+bkA]; vb.w=e[(4*j+3)*KCODES+bkB];
        o0[j]=va; o1[j]=vb;
    }

    red[tid] = bestA + bestB;
    __syncthreads();
    #pragma unroll
    for (int s2 = 128; s2 > 0; s2 >>= 1) {
        if (tid < s2) red[tid] += red[tid + s2];
        __syncthreads();
    }
    if (tid == 0) atomicAdd(loss_slot, red[0] * (1.25f / ((float)N_ROWS * (float)DIM)));
}

extern "C" void kernel_launch(void* const* d_in, const int* in_sizes, int n_in,
                              void* d_out, int out_size, void* d_ws, size_t ws_size,
                              hipStream_t stream) {
    const float* x = (const float*)d_in[0];   // [N, D]
    const float* e = (const float*)d_in[1];   // [D, K]
    float* out = (float*)d_out;               // N*D quantized + 1 loss
    float* loss_slot = out + (size_t)N_ROWS * DIM;

    // ws: eT f32 @0 (131072) | Bc bf16 @131072 (131072) | e2h @262144 (2048)
    const size_t ws_needed = 131072 + 131072 + 2048;

    if (ws_size >= ws_needed) {
        float* eT = (float*)d_ws;
        short* Bc = (short*)((char*)d_ws + 131072);
        float* e2h = (float*)((char*)d_ws + 262144);
        vq_init<<<128, 256, 0, stream>>>(e, eT, Bc, e2h, loss_slot);
        vq_mfma<<<N_ROWS / 256, 256, 0, stream>>>(x, e, eT, Bc, e2h, out, loss_slot);
    } else {
        vq_zero_loss<<<1, 1, 0, stream>>>(loss_slot);
        vq_scalar<<<N_ROWS / 512, 256, 0, stream>>>(x, e, out, loss_slot);
    }
}